// Round 1
// baseline (2360.655 us; speedup 1.0000x reference)
//
#include <hip/hip_runtime.h>
#include <hip/hip_bf16.h>

// Problem: B=16, C=512, H=W=64 -> N=4096, HEADS=8, d=64. All fp32.
// qkv[b,o,n] = sum_c w_qkv[o,c] x[b,c,n]; o = h*192 + which*64 + i
// k = softmax over n; q = softmax over i (d)
// ctx[b,h,i,j] = sum_n k[i,n] v[j,n]
// out[b, h*64+j, n] = sum_i ctx[i,j] q[i,n]
// y = x + w_proj @ out

#define NFULL 4096
#define QKVN 6291456L   // 1536*4096 per-batch qkv floats
#define CNF  2097152L   // 512*4096 per-batch x/out floats
#define CTXPF 262144L   // 8 heads * 8 splits * 4096 per-batch ctx-partial floats

// ---------------- generic 64x64-tile fp32 GEMM: C[o,n] = sum_k A[o,k]*B[k,n] (+x) ---
template<bool ADD_RES>
__global__ __launch_bounds__(256) void gemm64_kernel(
    const float* __restrict__ A,    // O x K row-major (shared across batch)
    const float* __restrict__ Bm,   // chunk base, per-batch stride strideB, K x 4096
    const float* __restrict__ Res,  // chunk base, per-batch stride strideC (or null)
    float* __restrict__ Cm,         // chunk base, per-batch stride strideC
    int K, long strideB, long strideC)
{
  __shared__ float As[16][64];
  __shared__ float Bs[16][64];
  const int bb = blockIdx.z;
  const int o0 = blockIdx.y * 64;
  const int n0 = blockIdx.x * 64;
  const float* Bb = Bm + (long)bb * strideB;
  float* Cb = Cm + (long)bb * strideC;
  const int t = threadIdx.x;
  const int tx = t & 15, ty = t >> 4;
  const int ar = t >> 2;        // 0..63 A row in tile
  const int ac = (t & 3) * 4;   // 0,4,8,12
  const int br = t >> 4;        // 0..15 B row in tile
  const int bc = (t & 15) * 4;  // 0..60

  float acc[4][4] = {};
  for (int k0 = 0; k0 < K; k0 += 16) {
    float4 av = *reinterpret_cast<const float4*>(&A[(long)(o0 + ar) * K + k0 + ac]);
    float4 bv = *reinterpret_cast<const float4*>(&Bb[(long)(k0 + br) * NFULL + n0 + bc]);
    __syncthreads();
    As[ac + 0][ar] = av.x;
    As[ac + 1][ar] = av.y;
    As[ac + 2][ar] = av.z;
    As[ac + 3][ar] = av.w;
    *reinterpret_cast<float4*>(&Bs[br][bc]) = bv;
    __syncthreads();
#pragma unroll
    for (int k = 0; k < 16; ++k) {
      float4 a4 = *reinterpret_cast<const float4*>(&As[k][ty * 4]);
      float4 b4 = *reinterpret_cast<const float4*>(&Bs[k][tx * 4]);
      float a_[4] = {a4.x, a4.y, a4.z, a4.w};
      float b_[4] = {b4.x, b4.y, b4.z, b4.w};
#pragma unroll
      for (int i = 0; i < 4; ++i)
#pragma unroll
        for (int j = 0; j < 4; ++j)
          acc[i][j] += a_[i] * b_[j];
    }
  }
#pragma unroll
  for (int i = 0; i < 4; ++i) {
    long off = (long)(o0 + ty * 4 + i) * NFULL + n0 + tx * 4;
    float4 r = make_float4(acc[i][0], acc[i][1], acc[i][2], acc[i][3]);
    if (ADD_RES) {
      float4 x4 = *reinterpret_cast<const float4*>(&Res[(long)bb * strideC + off]);
      r.x += x4.x; r.y += x4.y; r.z += x4.z; r.w += x4.w;
    }
    *reinterpret_cast<float4*>(&Cb[off]) = r;
  }
}

// ---------------- softmax of k rows over N=4096 (in place) --------------------------
// grid(512, nb) block 256; blockIdx.x = h*64 + i
__global__ __launch_bounds__(256) void ksoftmax_kernel(float* __restrict__ qkv)
{
  __shared__ float red[256];
  const int row = blockIdx.x, bb = blockIdx.y;
  const int h = row >> 6, i = row & 63;
  float* p = qkv + (long)bb * QKVN + (long)(h * 192 + 64 + i) * NFULL;
  const int t = threadIdx.x;
  float4 v[4];
  float m = -1e30f;
#pragma unroll
  for (int r = 0; r < 4; ++r) {
    v[r] = *reinterpret_cast<const float4*>(p + (r * 256 + t) * 4);
    m = fmaxf(m, fmaxf(fmaxf(v[r].x, v[r].y), fmaxf(v[r].z, v[r].w)));
  }
  red[t] = m; __syncthreads();
  for (int s = 128; s > 0; s >>= 1) {
    if (t < s) red[t] = fmaxf(red[t], red[t + s]);
    __syncthreads();
  }
  m = red[0];
  __syncthreads();
  float s = 0.f;
#pragma unroll
  for (int r = 0; r < 4; ++r) {
    v[r].x = __expf(v[r].x - m); v[r].y = __expf(v[r].y - m);
    v[r].z = __expf(v[r].z - m); v[r].w = __expf(v[r].w - m);
    s += v[r].x + v[r].y + v[r].z + v[r].w;
  }
  red[t] = s; __syncthreads();
  for (int s2 = 128; s2 > 0; s2 >>= 1) {
    if (t < s2) red[t] += red[t + s2];
    __syncthreads();
  }
  const float inv = 1.0f / red[0];
#pragma unroll
  for (int r = 0; r < 4; ++r) {
    v[r].x *= inv; v[r].y *= inv; v[r].z *= inv; v[r].w *= inv;
    *reinterpret_cast<float4*>(p + (r * 256 + t) * 4) = v[r];
  }
}

// ---------------- softmax of q over d=64 (in place) ---------------------------------
// grid(16, 8, nb) block 256; one thread per n
__global__ __launch_bounds__(256) void qsoftmax_kernel(float* __restrict__ qkv)
{
  const int t = threadIdx.x;
  const int n = blockIdx.x * 256 + t;
  const int h = blockIdx.y, bb = blockIdx.z;
  float* base = qkv + (long)bb * QKVN + (long)(h * 192) * NFULL + n;
  float v[64];
  float m = -1e30f;
#pragma unroll
  for (int i = 0; i < 64; ++i) { v[i] = base[(long)i * NFULL]; m = fmaxf(m, v[i]); }
  float s = 0.f;
#pragma unroll
  for (int i = 0; i < 64; ++i) { v[i] = __expf(v[i] - m); s += v[i]; }
  const float inv = 1.0f / s;
#pragma unroll
  for (int i = 0; i < 64; ++i) base[(long)i * NFULL] = v[i] * inv;
}

// ---------------- ctx split-K partials: ctxp[bb,h,s,i,j] = sum_{n in split s} k[i,n]v[j,n]
// grid(8, 8, nb) block 256
__global__ __launch_bounds__(256) void ctx_partial_kernel(
    const float* __restrict__ qkv, float* __restrict__ ctxp)
{
  __shared__ float Ks[64][33];
  __shared__ float Vs[64][33];
  const int s = blockIdx.x, h = blockIdx.y, bb = blockIdx.z;
  const float* kb = qkv + (long)bb * QKVN + (long)(h * 192 + 64) * NFULL;
  const float* vb = qkv + (long)bb * QKVN + (long)(h * 192 + 128) * NFULL;
  const int t = threadIdx.x;
  const int tx = t & 15, ty = t >> 4;
  const int lr = t >> 3;        // 0..31
  const int lc = (t & 7) * 4;   // 0..28
  float acc[4][4] = {};
  for (int n0 = s * 512; n0 < (s + 1) * 512; n0 += 32) {
    __syncthreads();
#pragma unroll
    for (int half = 0; half < 2; ++half) {
      const int r = lr + half * 32;
      float4 kv = *reinterpret_cast<const float4*>(&kb[(long)r * NFULL + n0 + lc]);
      float4 vv = *reinterpret_cast<const float4*>(&vb[(long)r * NFULL + n0 + lc]);
      Ks[r][lc] = kv.x; Ks[r][lc + 1] = kv.y; Ks[r][lc + 2] = kv.z; Ks[r][lc + 3] = kv.w;
      Vs[r][lc] = vv.x; Vs[r][lc + 1] = vv.y; Vs[r][lc + 2] = vv.z; Vs[r][lc + 3] = vv.w;
    }
    __syncthreads();
#pragma unroll
    for (int n = 0; n < 32; ++n) {
      float a_[4], b_[4];
#pragma unroll
      for (int ii = 0; ii < 4; ++ii) a_[ii] = Ks[ty * 4 + ii][n];
#pragma unroll
      for (int jj = 0; jj < 4; ++jj) b_[jj] = Vs[tx * 4 + jj][n];
#pragma unroll
      for (int ii = 0; ii < 4; ++ii)
#pragma unroll
        for (int jj = 0; jj < 4; ++jj)
          acc[ii][jj] += a_[ii] * b_[jj];
    }
  }
  float* cp = ctxp + (((long)(bb * 8 + h)) * 8 + s) * 4096;
#pragma unroll
  for (int ii = 0; ii < 4; ++ii)
#pragma unroll
    for (int jj = 0; jj < 4; ++jj)
      cp[(ty * 4 + ii) * 64 + tx * 4 + jj] = acc[ii][jj];
}

// ---------------- out[bb, h*64+j, n] = sum_i ctx[i,j] q[i,n] ------------------------
// grid(16, 8, nb) block 256; one thread per n
__global__ __launch_bounds__(256) void out_kernel(
    const float* __restrict__ qkv, const float* __restrict__ ctxp,
    float* __restrict__ outbuf)
{
  __shared__ float ctxs[4096];
  const int t = threadIdx.x;
  const int h = blockIdx.y, bb = blockIdx.z;
  const float* cp = ctxp + ((long)(bb * 8 + h)) * 8 * 4096;
#pragma unroll
  for (int e = 0; e < 16; ++e) {
    const int idx = e * 256 + t;
    float sum = 0.f;
#pragma unroll
    for (int s = 0; s < 8; ++s) sum += cp[s * 4096 + idx];
    ctxs[idx] = sum;
  }
  __syncthreads();
  const float* qbase = qkv + (long)bb * QKVN + (long)(h * 192) * NFULL;
  const int n = blockIdx.x * 256 + t;
  float acc[64] = {};
  for (int i = 0; i < 64; ++i) {
    const float qv = qbase[(long)i * NFULL + n];
#pragma unroll
    for (int j = 0; j < 64; ++j) acc[j] += ctxs[i * 64 + j] * qv;
  }
  float* ob = outbuf + (long)bb * CNF + (long)h * 64 * NFULL + n;
#pragma unroll
  for (int j = 0; j < 64; ++j) ob[(long)j * NFULL] = acc[j];
}

extern "C" void kernel_launch(void* const* d_in, const int* in_sizes, int n_in,
                              void* d_out, int out_size, void* d_ws, size_t ws_size,
                              hipStream_t stream)
{
  const float* x      = (const float*)d_in[0];
  const float* w_qkv  = (const float*)d_in[1];
  const float* w_proj = (const float*)d_in[2];
  float* out = (float*)d_out;

  const int B = 16;
  const long perBatch = QKVN + CNF + CTXPF;          // floats per batch of scratch
  const size_t perBytes = (size_t)perBatch * 4;
  int CB = (int)(ws_size / perBytes);
  if (CB > B) CB = B;
  if (CB < 1) CB = 1;   // assume ws is at least ~34 MB

  float* qkvbuf = (float*)d_ws;
  float* outbuf = qkvbuf + (long)CB * QKVN;
  float* ctxp   = outbuf + (long)CB * CNF;

  for (int b0 = 0; b0 < B; b0 += CB) {
    const int nb = (B - b0) < CB ? (B - b0) : CB;
    // 1. qkv = w_qkv @ x[b]
    gemm64_kernel<false><<<dim3(64, 24, nb), 256, 0, stream>>>(
        w_qkv, x + (long)b0 * CNF, nullptr, qkvbuf, 512, CNF, QKVN);
    // 2. softmax k over n
    ksoftmax_kernel<<<dim3(512, nb), 256, 0, stream>>>(qkvbuf);
    // 3. softmax q over d
    qsoftmax_kernel<<<dim3(16, 8, nb), 256, 0, stream>>>(qkvbuf);
    // 4. ctx partials
    ctx_partial_kernel<<<dim3(8, 8, nb), 256, 0, stream>>>(qkvbuf, ctxp);
    // 5. out = ctx^T q
    out_kernel<<<dim3(16, 8, nb), 256, 0, stream>>>(qkvbuf, ctxp, outbuf);
    // 6. y = x + w_proj @ out
    gemm64_kernel<true><<<dim3(64, 8, nb), 256, 0, stream>>>(
        w_proj, outbuf, x + (long)b0 * CNF, out + (long)b0 * CNF, 512, CNF, CNF);
  }
}

// Round 2
// 904.929 us; speedup vs baseline: 2.6087x; 2.6087x over previous
//
#include <hip/hip_runtime.h>
#include <hip/hip_bf16.h>

// B=16, C=512, H=W=64 -> N=4096, HEADS=8, d=64. fp32 in/out.
// Pipeline per batch chunk:
//   xT = transpose+f16(x)                      [n][c]
//   qkv[o][n] = w_qkv_f16[o][k] * xT[n][k]     (MFMA f16, fp32 acc)
//   k-softmax over n, q-softmax over d          (fp32, in place)
//   ctxp split-K partials (fp32 vector)
//   outT[n][c] = f16(sum_i ctx[i,j] q[i,n])
//   y[o][n] = x[o][n] + w_proj_f16[o][k]*outT[n][k]  (MFMA f16)

#define NFULL 4096
#define QKVN 6291456L   // 1536*4096 per-batch qkv floats
#define CNF  2097152L   // 512*4096 per-batch elements (x fp32 / xT,outT f16)
#define CTXPF 262144L   // 8 heads * 8 splits * 64*64 per-batch ctx-partial floats

typedef _Float16 half8 __attribute__((ext_vector_type(8)));
typedef _Float16 half4 __attribute__((ext_vector_type(4)));
typedef float floatx4 __attribute__((ext_vector_type(4)));

__device__ inline void async_copy16(const _Float16* g, _Float16* l) {
  __builtin_amdgcn_global_load_lds(
      (const __attribute__((address_space(1))) void*)g,
      (__attribute__((address_space(3))) void*)l,
      16, 0, 0);
}

// ---------------- f32 -> f16 weight conversion (vectorized x4) ----------------------
__global__ __launch_bounds__(256) void convert_w_kernel(
    const float* __restrict__ src, _Float16* __restrict__ dst, int n4)
{
  const int i = blockIdx.x * 256 + threadIdx.x;
  if (i < n4) {
    float4 v = reinterpret_cast<const float4*>(src)[i];
    half4 h = {(_Float16)v.x, (_Float16)v.y, (_Float16)v.z, (_Float16)v.w};
    reinterpret_cast<half4*>(dst)[i] = h;
  }
}

// ---------------- x[b][c][n] fp32 -> xT[b][n][c] f16 (64x64 LDS tile) ---------------
__global__ __launch_bounds__(256) void transpose_x_kernel(
    const float* __restrict__ x, _Float16* __restrict__ xT)
{
  __shared__ _Float16 tile[64][68];
  const int bb = blockIdx.z, c0 = blockIdx.y * 64, n0 = blockIdx.x * 64;
  const int t = threadIdx.x;
  const int rr0 = t >> 4;          // 0..15
  const int col4 = (t & 15) * 4;   // 0..60
  const float* xb = x + (long)bb * CNF;
#pragma unroll
  for (int p = 0; p < 4; ++p) {
    const int row = p * 16 + rr0;  // c within tile
    float4 v = *reinterpret_cast<const float4*>(&xb[(long)(c0 + row) * NFULL + n0 + col4]);
    tile[col4 + 0][row] = (_Float16)v.x;
    tile[col4 + 1][row] = (_Float16)v.y;
    tile[col4 + 2][row] = (_Float16)v.z;
    tile[col4 + 3][row] = (_Float16)v.w;
  }
  __syncthreads();
  _Float16* xTb = xT + (long)bb * CNF;
#pragma unroll
  for (int p = 0; p < 4; ++p) {
    const int nrow = p * 16 + rr0; // n within tile
    half4 h = *reinterpret_cast<const half4*>(&tile[nrow][col4]);
    *reinterpret_cast<half4*>(&xTb[(long)(n0 + nrow) * 512 + c0 + col4]) = h;
  }
}

// ---------------- MFMA f16 GEMM: C[o][n] = sum_k A[o][k] * Bt[n][k] (+Res) ----------
// 128x128 tile, BK=32, 256 threads = 4 waves, each wave 64x64 (4x4 of 16x16x32).
template<bool ADD_RES>
__global__ __launch_bounds__(256) void mfma_gemm_kernel(
    const _Float16* __restrict__ A,    // O x K row-major, shared across batch
    const _Float16* __restrict__ Bt,   // per-batch N x K row-major, stride strideB elems
    const float* __restrict__ Res,     // per-batch [o][n] fp32, stride strideC (or null)
    float* __restrict__ Cm,            // per-batch [o][n] fp32, stride strideC
    int K, long strideB, long strideC)
{
  __shared__ __align__(16) _Float16 As[128 * 32];
  __shared__ __align__(16) _Float16 Bs[128 * 32];
  const int bb = blockIdx.z;
  const int o0 = blockIdx.y * 128;
  const int n0 = blockIdx.x * 128;
  const _Float16* Bb = Bt + (long)bb * strideB;
  const int t = threadIdx.x;
  const int wave = t >> 6, lane = t & 63;
  const int wm = (wave >> 1) * 64, wn = (wave & 1) * 64;
  const int lr = lane >> 2;        // 0..15 row-in-segment
  const int lk = (lane & 3) * 8;   // 0,8,16,24 k-elems

  floatx4 acc[4][4];
#pragma unroll
  for (int mi = 0; mi < 4; ++mi)
#pragma unroll
    for (int ni = 0; ni < 4; ++ni)
      acc[mi][ni] = (floatx4){0.f, 0.f, 0.f, 0.f};

  const int lm = lane & 15;        // fragment row/col within 16
  const int lq = lane >> 4;        // quad 0..3

  for (int k0 = 0; k0 < K; k0 += 32) {
    __syncthreads();
#pragma unroll
    for (int q = 0; q < 2; ++q) {
      const int seg = wave * 2 + q;           // 0..7, 16 rows each
      const int r = seg * 16 + lr;
      async_copy16(&A[(long)(o0 + r) * K + k0 + lk], &As[seg * 512]);
      async_copy16(&Bb[(long)(n0 + r) * K + k0 + lk], &Bs[seg * 512]);
    }
    __syncthreads();
    half8 af[4], bf[4];
#pragma unroll
    for (int mi = 0; mi < 4; ++mi)
      af[mi] = *reinterpret_cast<const half8*>(&As[(wm + mi * 16 + lm) * 32 + lq * 8]);
#pragma unroll
    for (int ni = 0; ni < 4; ++ni)
      bf[ni] = *reinterpret_cast<const half8*>(&Bs[(wn + ni * 16 + lm) * 32 + lq * 8]);
#pragma unroll
    for (int mi = 0; mi < 4; ++mi)
#pragma unroll
      for (int ni = 0; ni < 4; ++ni)
        acc[mi][ni] = __builtin_amdgcn_mfma_f32_16x16x32_f16(af[mi], bf[ni], acc[mi][ni], 0, 0, 0);
  }

  // Epilogue: D[row][col], col = lane&15, row = quad*4 + reg  (m89-verified layout)
  float* Cb = Cm + (long)bb * strideC;
  const float* Rb = ADD_RES ? Res + (long)bb * strideC : nullptr;
#pragma unroll
  for (int mi = 0; mi < 4; ++mi) {
#pragma unroll
    for (int reg = 0; reg < 4; ++reg) {
      const long orow = o0 + wm + mi * 16 + lq * 4 + reg;
#pragma unroll
      for (int ni = 0; ni < 4; ++ni) {
        const long off = orow * NFULL + n0 + wn + ni * 16 + lm;
        float v = acc[mi][ni][reg];
        if (ADD_RES) v += Rb[off];
        Cb[off] = v;
      }
    }
  }
}

// ---------------- softmax of k rows over N=4096 (in place, fp32) --------------------
__global__ __launch_bounds__(256) void ksoftmax_kernel(float* __restrict__ qkv)
{
  __shared__ float red[256];
  const int row = blockIdx.x, bb = blockIdx.y;
  const int h = row >> 6, i = row & 63;
  float* p = qkv + (long)bb * QKVN + (long)(h * 192 + 64 + i) * NFULL;
  const int t = threadIdx.x;
  float4 v[4];
  float m = -1e30f;
#pragma unroll
  for (int r = 0; r < 4; ++r) {
    v[r] = *reinterpret_cast<const float4*>(p + (r * 256 + t) * 4);
    m = fmaxf(m, fmaxf(fmaxf(v[r].x, v[r].y), fmaxf(v[r].z, v[r].w)));
  }
  red[t] = m; __syncthreads();
  for (int s = 128; s > 0; s >>= 1) {
    if (t < s) red[t] = fmaxf(red[t], red[t + s]);
    __syncthreads();
  }
  m = red[0];
  __syncthreads();
  float s = 0.f;
#pragma unroll
  for (int r = 0; r < 4; ++r) {
    v[r].x = __expf(v[r].x - m); v[r].y = __expf(v[r].y - m);
    v[r].z = __expf(v[r].z - m); v[r].w = __expf(v[r].w - m);
    s += v[r].x + v[r].y + v[r].z + v[r].w;
  }
  red[t] = s; __syncthreads();
  for (int s2 = 128; s2 > 0; s2 >>= 1) {
    if (t < s2) red[t] += red[t + s2];
    __syncthreads();
  }
  const float inv = 1.0f / red[0];
#pragma unroll
  for (int r = 0; r < 4; ++r) {
    v[r].x *= inv; v[r].y *= inv; v[r].z *= inv; v[r].w *= inv;
    *reinterpret_cast<float4*>(p + (r * 256 + t) * 4) = v[r];
  }
}

// ---------------- softmax of q over d=64 (in place, fp32) ---------------------------
__global__ __launch_bounds__(256) void qsoftmax_kernel(float* __restrict__ qkv)
{
  const int t = threadIdx.x;
  const int n = blockIdx.x * 256 + t;
  const int h = blockIdx.y, bb = blockIdx.z;
  float* base = qkv + (long)bb * QKVN + (long)(h * 192) * NFULL + n;
  float v[64];
  float m = -1e30f;
#pragma unroll
  for (int i = 0; i < 64; ++i) { v[i] = base[(long)i * NFULL]; m = fmaxf(m, v[i]); }
  float s = 0.f;
#pragma unroll
  for (int i = 0; i < 64; ++i) { v[i] = __expf(v[i] - m); s += v[i]; }
  const float inv = 1.0f / s;
#pragma unroll
  for (int i = 0; i < 64; ++i) base[(long)i * NFULL] = v[i] * inv;
}

// ---------------- ctx split-K partials ----------------------------------------------
__global__ __launch_bounds__(256) void ctx_partial_kernel(
    const float* __restrict__ qkv, float* __restrict__ ctxp)
{
  __shared__ float Ks[64][33];
  __shared__ float Vs[64][33];
  const int s = blockIdx.x, h = blockIdx.y, bb = blockIdx.z;
  const float* kb = qkv + (long)bb * QKVN + (long)(h * 192 + 64) * NFULL;
  const float* vb = qkv + (long)bb * QKVN + (long)(h * 192 + 128) * NFULL;
  const int t = threadIdx.x;
  const int tx = t & 15, ty = t >> 4;
  const int lr = t >> 3;
  const int lc = (t & 7) * 4;
  float acc[4][4] = {};
  for (int n0 = s * 512; n0 < (s + 1) * 512; n0 += 32) {
    __syncthreads();
#pragma unroll
    for (int half = 0; half < 2; ++half) {
      const int r = lr + half * 32;
      float4 kv = *reinterpret_cast<const float4*>(&kb[(long)r * NFULL + n0 + lc]);
      float4 vv = *reinterpret_cast<const float4*>(&vb[(long)r * NFULL + n0 + lc]);
      Ks[r][lc] = kv.x; Ks[r][lc + 1] = kv.y; Ks[r][lc + 2] = kv.z; Ks[r][lc + 3] = kv.w;
      Vs[r][lc] = vv.x; Vs[r][lc + 1] = vv.y; Vs[r][lc + 2] = vv.z; Vs[r][lc + 3] = vv.w;
    }
    __syncthreads();
#pragma unroll
    for (int n = 0; n < 32; ++n) {
      float a_[4], b_[4];
#pragma unroll
      for (int ii = 0; ii < 4; ++ii) a_[ii] = Ks[ty * 4 + ii][n];
#pragma unroll
      for (int jj = 0; jj < 4; ++jj) b_[jj] = Vs[tx * 4 + jj][n];
#pragma unroll
      for (int ii = 0; ii < 4; ++ii)
#pragma unroll
        for (int jj = 0; jj < 4; ++jj)
          acc[ii][jj] += a_[ii] * b_[jj];
    }
  }
  float* cp = ctxp + (((long)(bb * 8 + h)) * 8 + s) * 4096;
#pragma unroll
  for (int ii = 0; ii < 4; ++ii)
#pragma unroll
    for (int jj = 0; jj < 4; ++jj)
      cp[(ty * 4 + ii) * 64 + tx * 4 + jj] = acc[ii][jj];
}

// ---------------- outT[n][h*64+j] = f16( sum_i ctx[i,j] q[i,n] ) --------------------
__global__ __launch_bounds__(256) void out_kernel(
    const float* __restrict__ qkv, const float* __restrict__ ctxp,
    _Float16* __restrict__ outT)
{
  __shared__ float ctxs[4096];
  const int t = threadIdx.x;
  const int h = blockIdx.y, bb = blockIdx.z;
  const float* cp = ctxp + ((long)(bb * 8 + h)) * 8 * 4096;
#pragma unroll
  for (int e = 0; e < 16; ++e) {
    const int idx = e * 256 + t;
    float sum = 0.f;
#pragma unroll
    for (int s = 0; s < 8; ++s) sum += cp[s * 4096 + idx];
    ctxs[idx] = sum;
  }
  __syncthreads();
  const float* qbase = qkv + (long)bb * QKVN + (long)(h * 192) * NFULL;
  const int n = blockIdx.x * 256 + t;
  float acc[64] = {};
  for (int i = 0; i < 64; ++i) {
    const float qv = qbase[(long)i * NFULL + n];
#pragma unroll
    for (int j = 0; j < 64; ++j) acc[j] += ctxs[i * 64 + j] * qv;
  }
  _Float16* ob = outT + (long)bb * CNF + (long)n * 512 + h * 64;
#pragma unroll
  for (int j8 = 0; j8 < 8; ++j8) {
    half8 sv;
#pragma unroll
    for (int e = 0; e < 8; ++e) sv[e] = (_Float16)acc[j8 * 8 + e];
    *reinterpret_cast<half8*>(&ob[j8 * 8]) = sv;
  }
}

extern "C" void kernel_launch(void* const* d_in, const int* in_sizes, int n_in,
                              void* d_out, int out_size, void* d_ws, size_t ws_size,
                              hipStream_t stream)
{
  const float* x      = (const float*)d_in[0];
  const float* w_qkv  = (const float*)d_in[1];
  const float* w_proj = (const float*)d_in[2];
  float* out = (float*)d_out;

  const int B = 16;
  const long WQ = 1536L * 512, WP = 512L * 512;
  // workspace layout: [wqh f16][wph f16] then per-chunk [qkv f32][xT f16][outT f16][ctxp f32]
  const size_t wBytes = (size_t)(WQ + WP) * 2;
  const size_t perBytes = (size_t)QKVN * 4 + (size_t)CNF * 2 * 2 + (size_t)CTXPF * 4;
  int CB = (int)((ws_size > wBytes ? ws_size - wBytes : 0) / perBytes);
  if (CB > B) CB = B;
  if (CB < 1) CB = 1;

  _Float16* wqh = (_Float16*)d_ws;
  _Float16* wph = wqh + WQ;
  char* base = (char*)(wph + WP);
  float*    qkvbuf = (float*)base;
  _Float16* xT     = (_Float16*)(base + (size_t)CB * QKVN * 4);
  _Float16* outT   = xT + (long)CB * CNF;
  float*    ctxp   = (float*)((char*)(outT + (long)CB * CNF));

  // weight conversion (once per launch)
  convert_w_kernel<<<dim3((int)(WQ / 4 + 255) / 256), 256, 0, stream>>>(w_qkv, wqh, (int)(WQ / 4));
  convert_w_kernel<<<dim3((int)(WP / 4 + 255) / 256), 256, 0, stream>>>(w_proj, wph, (int)(WP / 4));

  for (int b0 = 0; b0 < B; b0 += CB) {
    const int nb = (B - b0) < CB ? (B - b0) : CB;
    const float* xc = x + (long)b0 * CNF;
    // 0. xT = transpose+f16(x)
    transpose_x_kernel<<<dim3(64, 8, nb), 256, 0, stream>>>(xc, xT);
    // 1. qkv = w_qkv @ x  (MFMA)
    mfma_gemm_kernel<false><<<dim3(32, 12, nb), 256, 0, stream>>>(
        wqh, xT, nullptr, qkvbuf, 512, CNF, QKVN);
    // 2. softmax k over n
    ksoftmax_kernel<<<dim3(512, nb), 256, 0, stream>>>(qkvbuf);
    // 3. softmax q over d
    qsoftmax_kernel<<<dim3(16, 8, nb), 256, 0, stream>>>(qkvbuf);
    // 4. ctx partials
    ctx_partial_kernel<<<dim3(8, 8, nb), 256, 0, stream>>>(qkvbuf, ctxp);
    // 5. outT = f16(ctx^T q)
    out_kernel<<<dim3(16, 8, nb), 256, 0, stream>>>(qkvbuf, ctxp, outT);
    // 6. y = x + w_proj @ out  (MFMA)
    mfma_gemm_kernel<true><<<dim3(32, 4, nb), 256, 0, stream>>>(
        wph, outT, xc, out + (long)b0 * CNF, 512, CNF, CNF);
  }
}

// Round 3
// 600.451 us; speedup vs baseline: 3.9315x; 1.5071x over previous
//
#include <hip/hip_runtime.h>
#include <hip/hip_bf16.h>

// B=16, C=512, H=W=64 -> N=4096, HEADS=8, d=64. fp32 in/out.
// Restructured pipeline (exp fused into GEMM epilogue, proj folded through ctx):
//   xT = f16(x^T)                                   [b][n][c]
//   QKV GEMM (MFMA f16): emits eqT[b][n][hi]=exp(q), ek[b][hi][n]=exp(k), vv[b][hi][n]=v
//   qnorm: eqT /= per-(n,h) colsum                  (softmax over d, exp pre-applied)
//   ctx_partial: ctxp[b,h,s] = ek_slice @ vv_slice^T (+rowsum of ek)   MFMA f16
//   ctxm: ctxn = sum_s ctxp / rowsum; M[b][o][h*64+i] = sum_j wp[o][h*64+j] ctxn[i][j]
//   GEMM-2 (MFMA f16): y = x + M[b] @ eqT[b]^T

#define NFULL 4096L
#define XTN   2097152L   // 4096*512 per-batch f16 elems
#define CPSL  4160L      // per (b,h,s) ctx-partial floats: 64*64 + 64 rowsum

typedef _Float16 half8 __attribute__((ext_vector_type(8)));
typedef _Float16 half4 __attribute__((ext_vector_type(4)));
typedef float floatx4 __attribute__((ext_vector_type(4)));

__device__ inline void async_copy16(const _Float16* g, _Float16* l) {
  __builtin_amdgcn_global_load_lds(
      (const __attribute__((address_space(1))) void*)g,
      (__attribute__((address_space(3))) void*)l,
      16, 0, 0);
}

// ---------------- f32 -> f16 weight conversion ----------------------------------
__global__ __launch_bounds__(256) void convert_w_kernel(
    const float* __restrict__ src, _Float16* __restrict__ dst, int n4)
{
  const int i = blockIdx.x * 256 + threadIdx.x;
  if (i < n4) {
    float4 v = reinterpret_cast<const float4*>(src)[i];
    half4 h = {(_Float16)v.x, (_Float16)v.y, (_Float16)v.z, (_Float16)v.w};
    reinterpret_cast<half4*>(dst)[i] = h;
  }
}

// ---------------- x[b][c][n] fp32 -> xT[b][n][c] f16 ----------------------------
__global__ __launch_bounds__(256) void transpose_x_kernel(
    const float* __restrict__ x, _Float16* __restrict__ xT)
{
  __shared__ _Float16 tile[64][68];
  const int bb = blockIdx.z, c0 = blockIdx.y * 64, n0 = blockIdx.x * 64;
  const int t = threadIdx.x;
  const int rr0 = t >> 4;
  const int col4 = (t & 15) * 4;
  const float* xb = x + (long)bb * XTN;
#pragma unroll
  for (int p = 0; p < 4; ++p) {
    const int row = p * 16 + rr0;
    float4 v = *reinterpret_cast<const float4*>(&xb[(long)(c0 + row) * NFULL + n0 + col4]);
    tile[col4 + 0][row] = (_Float16)v.x;
    tile[col4 + 1][row] = (_Float16)v.y;
    tile[col4 + 2][row] = (_Float16)v.z;
    tile[col4 + 3][row] = (_Float16)v.w;
  }
  __syncthreads();
  _Float16* xTb = xT + (long)bb * XTN;
#pragma unroll
  for (int p = 0; p < 4; ++p) {
    const int nrow = p * 16 + rr0;
    half4 h = *reinterpret_cast<const half4*>(&tile[nrow][col4]);
    *reinterpret_cast<half4*>(&xTb[(long)(n0 + nrow) * 512 + c0 + col4]) = h;
  }
}

// ---------------- QKV GEMM + exp epilogue ---------------------------------------
// C[o][n] = sum_k wqh[o][k] xT[n][k];  o = h*192 + which*64 + i
__global__ __launch_bounds__(256) void qkv_gemm_exp_kernel(
    const _Float16* __restrict__ A,    // 1536 x 512
    const _Float16* __restrict__ xT,   // [b][n][512]
    _Float16* __restrict__ eqT,        // [b][n][512]  exp(q)
    _Float16* __restrict__ ek,         // [b][512][4096] exp(k)
    _Float16* __restrict__ vv)         // [b][512][4096] v
{
  __shared__ __align__(16) _Float16 As[128 * 32];
  __shared__ __align__(16) _Float16 Bs[128 * 32];
  const int bb = blockIdx.z;
  const int o0 = blockIdx.y * 128;
  const int n0 = blockIdx.x * 128;
  const _Float16* Bb = xT + (long)bb * XTN;
  const int t = threadIdx.x;
  const int wave = t >> 6, lane = t & 63;
  const int wm = (wave >> 1) * 64, wn = (wave & 1) * 64;
  const int lr = lane >> 2;
  const int lk = (lane & 3) * 8;
  const int lm = lane & 15, lq = lane >> 4;

  floatx4 acc[4][4];
#pragma unroll
  for (int mi = 0; mi < 4; ++mi)
#pragma unroll
    for (int ni = 0; ni < 4; ++ni)
      acc[mi][ni] = (floatx4){0.f, 0.f, 0.f, 0.f};

  for (int k0 = 0; k0 < 512; k0 += 32) {
    __syncthreads();
#pragma unroll
    for (int q = 0; q < 2; ++q) {
      const int seg = wave * 2 + q;
      const int r = seg * 16 + lr;
      async_copy16(&A[(long)(o0 + r) * 512 + k0 + lk], &As[seg * 512]);
      async_copy16(&Bb[(long)(n0 + r) * 512 + k0 + lk], &Bs[seg * 512]);
    }
    __syncthreads();
    half8 af[4], bf[4];
#pragma unroll
    for (int mi = 0; mi < 4; ++mi)
      af[mi] = *reinterpret_cast<const half8*>(&As[(wm + mi * 16 + lm) * 32 + lq * 8]);
#pragma unroll
    for (int ni = 0; ni < 4; ++ni)
      bf[ni] = *reinterpret_cast<const half8*>(&Bs[(wn + ni * 16 + lm) * 32 + lq * 8]);
#pragma unroll
    for (int mi = 0; mi < 4; ++mi)
#pragma unroll
      for (int ni = 0; ni < 4; ++ni)
        acc[mi][ni] = __builtin_amdgcn_mfma_f32_16x16x32_f16(af[mi], bf[ni], acc[mi][ni], 0, 0, 0);
  }

  // epilogue: D row = lq*4+reg (within 16-tile), col = lm
#pragma unroll
  for (int mi = 0; mi < 4; ++mi) {
    const int orow0 = o0 + wm + mi * 16 + lq * 4;   // 4-aligned, within one 64-block
    const int h = orow0 / 192;
    const int r = orow0 - h * 192;
    const int which = r >> 6;
    const int i0 = r & 63;
    if (which == 0) {
      // q: exp, transposed store, 4 consecutive f16 per lane
#pragma unroll
      for (int ni = 0; ni < 4; ++ni) {
        const long n = n0 + wn + ni * 16 + lm;
        half4 st;
#pragma unroll
        for (int reg = 0; reg < 4; ++reg)
          st[reg] = (_Float16)__expf(acc[mi][ni][reg]);
        *reinterpret_cast<half4*>(&eqT[((long)bb * NFULL + n) * 512 + h * 64 + i0]) = st;
      }
    } else {
      _Float16* dst = (which == 1) ? ek : vv;
#pragma unroll
      for (int reg = 0; reg < 4; ++reg) {
        const long row = (long)bb * 512 + h * 64 + i0 + reg;
#pragma unroll
        for (int ni = 0; ni < 4; ++ni) {
          const long n = n0 + wn + ni * 16 + lm;
          float v = acc[mi][ni][reg];
          if (which == 1) v = __expf(v);
          dst[row * NFULL + n] = (_Float16)v;
        }
      }
    }
  }
}

// ---------------- eqT softmax-over-d normalize (wave per (b,n)) -----------------
__global__ __launch_bounds__(256) void qnorm_kernel(_Float16* __restrict__ eqT)
{
  const int t = threadIdx.x;
  const int wv = t >> 6, lane = t & 63;
  const long gw = (long)blockIdx.x * 4 + wv;      // = bb*4096 + n
  _Float16* p = eqT + gw * 512 + lane * 8;
  half8 v = *reinterpret_cast<const half8*>(p);
  float s = 0.f;
#pragma unroll
  for (int e = 0; e < 8; ++e) s += (float)v[e];
  s += __shfl_xor(s, 1, 64);
  s += __shfl_xor(s, 2, 64);
  s += __shfl_xor(s, 4, 64);   // lanes 8k..8k+7 (one head) now share the sum
  const float inv = 1.0f / s;
#pragma unroll
  for (int e = 0; e < 8; ++e) v[e] = (_Float16)((float)v[e] * inv);
  *reinterpret_cast<half8*>(p) = v;
}

// ---------------- ctx split-K MFMA partials + k-rowsum --------------------------
// grid(8 ksplit, 8 h, 16 b), 256 thr = 4 waves each covering 128 of n
__global__ __launch_bounds__(256) void ctx_partial_kernel(
    const _Float16* __restrict__ ek, const _Float16* __restrict__ vv,
    float* __restrict__ ctxp)
{
  __shared__ float ctxs[64][65];
  __shared__ float rs[64];
  const int s = blockIdx.x, h = blockIdx.y, bb = blockIdx.z;
  const int t = threadIdx.x, wave = t >> 6, lane = t & 63;
  const int lm = lane & 15, lq = lane >> 4;
  const _Float16* ekb = ek + ((long)bb * 512 + h * 64) * NFULL;
  const _Float16* vvb = vv + ((long)bb * 512 + h * 64) * NFULL;

  floatx4 acc[4][4];
#pragma unroll
  for (int mi = 0; mi < 4; ++mi)
#pragma unroll
    for (int nj = 0; nj < 4; ++nj)
      acc[mi][nj] = (floatx4){0.f, 0.f, 0.f, 0.f};
  float rsum[4] = {0.f, 0.f, 0.f, 0.f};

  const int nbase = s * 512 + wave * 128;
#pragma unroll
  for (int kk = 0; kk < 4; ++kk) {
    const int k0 = nbase + kk * 32 + lq * 8;
    half8 af[4], bf[4];
#pragma unroll
    for (int mi = 0; mi < 4; ++mi)
      af[mi] = *reinterpret_cast<const half8*>(&ekb[(long)(mi * 16 + lm) * NFULL + k0]);
#pragma unroll
    for (int nj = 0; nj < 4; ++nj)
      bf[nj] = *reinterpret_cast<const half8*>(&vvb[(long)(nj * 16 + lm) * NFULL + k0]);
#pragma unroll
    for (int mi = 0; mi < 4; ++mi) {
      float ss = 0.f;
#pragma unroll
      for (int e = 0; e < 8; ++e) ss += (float)af[mi][e];
      rsum[mi] += ss;
    }
#pragma unroll
    for (int mi = 0; mi < 4; ++mi)
#pragma unroll
      for (int nj = 0; nj < 4; ++nj)
        acc[mi][nj] = __builtin_amdgcn_mfma_f32_16x16x32_f16(af[mi], bf[nj], acc[mi][nj], 0, 0, 0);
  }

  for (int e = t; e < 64 * 65; e += 256) (&ctxs[0][0])[e] = 0.f;
  if (t < 64) rs[t] = 0.f;
  __syncthreads();
#pragma unroll
  for (int mi = 0; mi < 4; ++mi)
    atomicAdd(&rs[mi * 16 + lm], rsum[mi]);
#pragma unroll
  for (int mi = 0; mi < 4; ++mi)
#pragma unroll
    for (int nj = 0; nj < 4; ++nj)
#pragma unroll
      for (int reg = 0; reg < 4; ++reg)
        atomicAdd(&ctxs[mi * 16 + lq * 4 + reg][nj * 16 + lm], acc[mi][nj][reg]);
  __syncthreads();
  float* cp = ctxp + (((long)(bb * 8 + h)) * 8 + s) * CPSL;
  for (int e = t; e < 4096; e += 256) cp[e] = ctxs[e >> 6][e & 63];
  if (t < 64) cp[4096 + t] = rs[t];
}

// ---------------- combine partials, normalize, M = wp_h @ ctxn^T ----------------
// grid(8 h, 16 b), 256 thr = 4 waves, each wave 128 o-rows
__global__ __launch_bounds__(256) void ctxm_kernel(
    const float* __restrict__ ctxp, const _Float16* __restrict__ wp,
    _Float16* __restrict__ M)
{
  __shared__ float rs[64];
  __shared__ _Float16 ctxh[64][72];
  const int h = blockIdx.x, bb = blockIdx.y;
  const int t = threadIdx.x, wave = t >> 6, lane = t & 63;
  const int lm = lane & 15, lq = lane >> 4;
  const float* cp = ctxp + (((long)(bb * 8 + h)) * 8) * CPSL;
  if (t < 64) {
    float s = 0.f;
#pragma unroll
    for (int ss = 0; ss < 8; ++ss) s += cp[ss * CPSL + 4096 + t];
    rs[t] = 1.0f / s;
  }
  __syncthreads();
  for (int e = t; e < 4096; e += 256) {
    float s = 0.f;
#pragma unroll
    for (int ss = 0; ss < 8; ++ss) s += cp[ss * CPSL + e];
    ctxh[e >> 6][e & 63] = (_Float16)(s * rs[e >> 6]);
  }
  __syncthreads();

  // M_bh[o][i] = sum_j wp[o][h*64+j] * ctxn[i][j]; m=o(128/wave), n=i(64), k=j(64)
  const _Float16* wpb = wp + h * 64;
  const int o0w = wave * 128;
  floatx4 acc[8][4];
#pragma unroll
  for (int mi = 0; mi < 8; ++mi)
#pragma unroll
    for (int ni = 0; ni < 4; ++ni)
      acc[mi][ni] = (floatx4){0.f, 0.f, 0.f, 0.f};
#pragma unroll
  for (int ks = 0; ks < 2; ++ks) {
    const int j0 = ks * 32 + lq * 8;
    half8 bfr[4];
#pragma unroll
    for (int ni = 0; ni < 4; ++ni)
      bfr[ni] = *reinterpret_cast<const half8*>(&ctxh[ni * 16 + lm][j0]);
#pragma unroll
    for (int mi = 0; mi < 8; ++mi) {
      half8 afr = *reinterpret_cast<const half8*>(&wpb[(long)(o0w + mi * 16 + lm) * 512 + j0]);
#pragma unroll
      for (int ni = 0; ni < 4; ++ni)
        acc[mi][ni] = __builtin_amdgcn_mfma_f32_16x16x32_f16(afr, bfr[ni], acc[mi][ni], 0, 0, 0);
    }
  }
  _Float16* Mb = M + (long)bb * 512 * 512;
#pragma unroll
  for (int mi = 0; mi < 8; ++mi)
#pragma unroll
    for (int reg = 0; reg < 4; ++reg) {
      const int o = o0w + mi * 16 + lq * 4 + reg;
#pragma unroll
      for (int ni = 0; ni < 4; ++ni)
        Mb[(long)o * 512 + h * 64 + ni * 16 + lm] = (_Float16)acc[mi][ni][reg];
    }
}

// ---------------- GEMM-2: y = x + M[b] @ eqT[b]^T -------------------------------
__global__ __launch_bounds__(256) void gemm2_kernel(
    const _Float16* __restrict__ M,    // [b][512][512]
    const _Float16* __restrict__ eqT,  // [b][4096][512] normalized
    const float* __restrict__ x, float* __restrict__ y)
{
  __shared__ __align__(16) _Float16 As[128 * 32];
  __shared__ __align__(16) _Float16 Bs[128 * 32];
  const int bb = blockIdx.z;
  const int o0 = blockIdx.y * 128;
  const int n0 = blockIdx.x * 128;
  const _Float16* Ab = M + (long)bb * 512 * 512;
  const _Float16* Bb = eqT + (long)bb * XTN;
  const int t = threadIdx.x;
  const int wave = t >> 6, lane = t & 63;
  const int wm = (wave >> 1) * 64, wn = (wave & 1) * 64;
  const int lr = lane >> 2;
  const int lk = (lane & 3) * 8;
  const int lm = lane & 15, lq = lane >> 4;

  floatx4 acc[4][4];
#pragma unroll
  for (int mi = 0; mi < 4; ++mi)
#pragma unroll
    for (int ni = 0; ni < 4; ++ni)
      acc[mi][ni] = (floatx4){0.f, 0.f, 0.f, 0.f};

  for (int k0 = 0; k0 < 512; k0 += 32) {
    __syncthreads();
#pragma unroll
    for (int q = 0; q < 2; ++q) {
      const int seg = wave * 2 + q;
      const int r = seg * 16 + lr;
      async_copy16(&Ab[(long)(o0 + r) * 512 + k0 + lk], &As[seg * 512]);
      async_copy16(&Bb[(long)(n0 + r) * 512 + k0 + lk], &Bs[seg * 512]);
    }
    __syncthreads();
    half8 af[4], bf[4];
#pragma unroll
    for (int mi = 0; mi < 4; ++mi)
      af[mi] = *reinterpret_cast<const half8*>(&As[(wm + mi * 16 + lm) * 32 + lq * 8]);
#pragma unroll
    for (int ni = 0; ni < 4; ++ni)
      bf[ni] = *reinterpret_cast<const half8*>(&Bs[(wn + ni * 16 + lm) * 32 + lq * 8]);
#pragma unroll
    for (int mi = 0; mi < 4; ++mi)
#pragma unroll
      for (int ni = 0; ni < 4; ++ni)
        acc[mi][ni] = __builtin_amdgcn_mfma_f32_16x16x32_f16(af[mi], bf[ni], acc[mi][ni], 0, 0, 0);
  }

  const float* Rb = x + (long)bb * XTN;
  float* Cb = y + (long)bb * XTN;
#pragma unroll
  for (int mi = 0; mi < 4; ++mi)
#pragma unroll
    for (int reg = 0; reg < 4; ++reg) {
      const long orow = o0 + wm + mi * 16 + lq * 4 + reg;
#pragma unroll
      for (int ni = 0; ni < 4; ++ni) {
        const long off = orow * NFULL + n0 + wn + ni * 16 + lm;
        Cb[off] = acc[mi][ni][reg] + Rb[off];
      }
    }
}

extern "C" void kernel_launch(void* const* d_in, const int* in_sizes, int n_in,
                              void* d_out, int out_size, void* d_ws, size_t ws_size,
                              hipStream_t stream)
{
  const float* x      = (const float*)d_in[0];
  const float* w_qkv  = (const float*)d_in[1];
  const float* w_proj = (const float*)d_in[2];
  float* out = (float*)d_out;

  const long WQ = 1536L * 512, WP = 512L * 512;
  char* p = (char*)d_ws;
  _Float16* wqh = (_Float16*)p; p += WQ * 2;
  _Float16* wph = (_Float16*)p; p += WP * 2;
  _Float16* xT  = (_Float16*)p; p += 16L * XTN * 2;
  _Float16* eqT = (_Float16*)p; p += 16L * XTN * 2;
  _Float16* ek  = (_Float16*)p; p += 16L * XTN * 2;
  _Float16* vv  = (_Float16*)p; p += 16L * XTN * 2;
  float* ctxp   = (float*)p;    p += 16L * 8 * 8 * CPSL * 4;
  _Float16* M   = (_Float16*)p;

  convert_w_kernel<<<dim3((int)(WQ / 4 + 255) / 256), 256, 0, stream>>>(w_qkv, wqh, (int)(WQ / 4));
  convert_w_kernel<<<dim3((int)(WP / 4 + 255) / 256), 256, 0, stream>>>(w_proj, wph, (int)(WP / 4));
  transpose_x_kernel<<<dim3(64, 8, 16), 256, 0, stream>>>(x, xT);
  qkv_gemm_exp_kernel<<<dim3(32, 12, 16), 256, 0, stream>>>(wqh, xT, eqT, ek, vv);
  qnorm_kernel<<<dim3(16384), 256, 0, stream>>>(eqT);
  ctx_partial_kernel<<<dim3(8, 8, 16), 256, 0, stream>>>(ek, vv, ctxp);
  ctxm_kernel<<<dim3(8, 16), 256, 0, stream>>>(ctxp, wph, M);
  gemm2_kernel<<<dim3(32, 4, 16), 256, 0, stream>>>(M, eqT, x, out);
}